// Round 24
// baseline (233.813 us; speedup 1.0000x reference)
//
#include <hip/hip_runtime.h>
#include <hip/hip_bf16.h>
#include <cstddef>

#define B_   4
#define S_   1500
#define D_   1280
#define H_   20
#define HD_  64
#define M_   (B_*S_)
#define SPAD 1536
#define BIGNEG (-1e30f)
#define LOG2E 1.44269504088896340736f
#define KVB  64
#define NTA  24   // ceil(1500/64)

typedef short bf16x8 __attribute__((ext_vector_type(8)));
typedef float f32x4 __attribute__((ext_vector_type(4)));
typedef unsigned short u16;
typedef u16 u16x8 __attribute__((ext_vector_type(8)));
typedef unsigned int u32x4v __attribute__((ext_vector_type(4)));

#define MFMA __builtin_amdgcn_mfma_f32_16x16x32_bf16

__device__ __forceinline__ u16 f2bf(float f) {
  union { float f; unsigned u; } x; x.f = f;
  unsigned r = (x.u + 0x7fffu + ((x.u >> 16) & 1u)) >> 16;
  return (u16)r;
}

__device__ __forceinline__ unsigned cvtpk(float a, float b) {
  unsigned r;
  asm volatile("v_cvt_pk_bf16_f32 %0, %1, %2" : "=v"(r) : "v"(a), "v"(b));
  return r;
}

__device__ __forceinline__ void gl_lds16(const u16* g, u16* l) {
  typedef __attribute__((address_space(1))) const unsigned GU;
  typedef __attribute__((address_space(3))) unsigned LU;
  __builtin_amdgcn_global_load_lds((GU*)g, (LU*)l, 16, 0, 0);
}

// ---- fused: fp32->bf16 convert (blocks 0..3749) + mask zero-scan (rest) ----
__global__ __launch_bounds__(256) void k_conv(const float* __restrict__ X, u16* __restrict__ Y,
                                              const float* __restrict__ msk, int* __restrict__ flag) {
  if (blockIdx.x < 3750) {
    size_t i = (size_t)blockIdx.x * 256 + threadIdx.x;
    const float4* p = (const float4*)(X + i * 8);
    float4 a = p[0], b = p[1];
    u16x8 v;
    v[0]=f2bf(a.x); v[1]=f2bf(a.y); v[2]=f2bf(a.z); v[3]=f2bf(a.w);
    v[4]=f2bf(b.x); v[5]=f2bf(b.y); v[6]=f2bf(b.z); v[7]=f2bf(b.w);
    *(u16x8*)(Y + i * 8) = v;
  } else {
    const size_t tot = (size_t)B_ * S_ * S_;
    size_t i = ((size_t)(blockIdx.x - 3750) * 256 + threadIdx.x) * 4;
    size_t stride = (size_t)1024 * 256 * 4;
    for (; i < tot; i += stride) {
      float4 v = *(const float4*)(msk + i);
      if (v.x != 0.f || v.y != 0.f || v.z != 0.f || v.w != 0.f) {
        int b = (int)(i / ((size_t)S_ * S_));
        atomicOr(&flag[b], 1);
      }
    }
  }
}

// ---- 4 weights W[k][n] fp32 -> Wt[n][k] bf16 transpose, z-selected ----
__global__ __launch_bounds__(256) void k_trans4(const float* __restrict__ qw,
                                                const float* __restrict__ kw,
                                                const float* __restrict__ vw,
                                                const float* __restrict__ ow,
                                                u16* __restrict__ Wt) {
  const float* W = (blockIdx.z == 0) ? qw : (blockIdx.z == 1) ? kw
                   : (blockIdx.z == 2) ? vw : ow;
  u16* dst = Wt + (size_t)blockIdx.z * D_ * D_;
  __shared__ float t[32][33];
  int n0 = blockIdx.x * 32, k0 = blockIdx.y * 32;
  int tx = threadIdx.x & 31, ty = threadIdx.x >> 5;
  #pragma unroll
  for (int i = ty; i < 32; i += 8) t[i][tx] = W[(size_t)(k0 + i) * D_ + n0 + tx];
  __syncthreads();
  #pragma unroll
  for (int i = ty; i < 32; i += 8) dst[(size_t)(n0 + i) * D_ + k0 + tx] = f2bf(t[tx][i]);
}

// ---- Fused QKV GEMM, XCD-chunked, m97 structure: BK=64, SINGLE 32KB buffer.
// sel==2 (V) epilogue writes slot-permuted Vt DIRECTLY (vtrans fused away). ----
__global__ __launch_bounds__(256) void k_gemmqkv(const u16* __restrict__ A,
                                                 const u16* __restrict__ Wt,
                                                 const float* __restrict__ q_b,
                                                 const float* __restrict__ v_b,
                                                 u16* __restrict__ Qb,
                                                 u16* __restrict__ Vt) {
  int p = blockIdx.x;
  int gg = p & 7;
  int idx = p >> 3;
  int y = idx / 6;
  int x = gg * 6 + idx % 6;
  if (x >= 47) return;

  __shared__ u16 As[128 * 64];
  __shared__ u16 Bs[128 * 64];
  int tid = threadIdx.x;
  int lane = tid & 63;
  int wv = tid >> 6;
  int l16 = lane & 15, lg = lane >> 4;
  int wr = wv >> 1, wc = wv & 1;
  int m0 = x * 128;
  int n0g = y * 128;
  int sel = y / 10;
  int nloc = n0g - sel * 1280;

  int srow = tid >> 3;
  int csw = ((tid & 7) ^ (srow & 7)) * 8;
  const u16* asrc = A + csw;
  const u16* bsrc = Wt + csw;
  int dbase = wv * 8 * 64;

  f32x4 acc[4][4] = {};

#define STAGEG(tt) do {                                                  \
    int kk0 = (tt) * 64;                                                 \
    _Pragma("unroll")                                                    \
    for (int c = 0; c < 4; c++) {                                        \
      int row = srow + c * 32;                                           \
      int ar = m0 + row; if (ar > M_ - 1) ar = M_ - 1;                   \
      gl_lds16(asrc + (size_t)ar * D_ + kk0, &As[0] + dbase + c * 2048); \
      gl_lds16(bsrc + (size_t)(n0g + row) * D_ + kk0,                    \
               &Bs[0] + dbase + c * 2048);                               \
    }                                                                    \
  } while (0)

  for (int t = 0; t < 20; t++) {
    STAGEG(t);
    __syncthreads();
    #pragma unroll
    for (int kk = 0; kk < 2; kk++) {
      int pcol = ((kk * 4 + lg) ^ (l16 & 7)) * 8;
      bf16x8 af[4], bf[4];
      #pragma unroll
      for (int m = 0; m < 4; m++)
        af[m] = *(const bf16x8*)&As[(wr * 64 + m * 16 + l16) * 64 + pcol];
      #pragma unroll
      for (int n = 0; n < 4; n++)
        bf[n] = *(const bf16x8*)&Bs[(wc * 64 + n * 16 + l16) * 64 + pcol];
      __builtin_amdgcn_s_setprio(1);
      #pragma unroll
      for (int m = 0; m < 4; m++)
        #pragma unroll
        for (int n = 0; n < 4; n++)
          acc[m][n] = MFMA(af[m], bf[n], acc[m][n], 0, 0, 0);
      __builtin_amdgcn_s_setprio(0);
    }
    __syncthreads();
  }
#undef STAGEG

  const float* bias = (sel == 0) ? q_b : v_b;
  float scl = (sel == 0) ? (0.125f * LOG2E) : 1.0f;
  u16* outb = Qb + (size_t)sel * ((size_t)M_ * D_);

  #pragma unroll
  for (int m = 0; m < 4; m++) {
    int row0 = m0 + wr * 64 + m * 16 + lg * 4;
    #pragma unroll
    for (int n = 0; n < 4; n++) {
      int colL = nloc + wc * 64 + n * 16 + l16;
      float bv = (sel == 1) ? 0.0f : bias[colL];
      #pragma unroll
      for (int j = 0; j < 4; j++) {
        int row = row0 + j;
        if (row < M_) {
          float v = (acc[m][n][j] + bv) * scl;
          if (sel == 2) {
            // direct slot-permuted Vt write (vtrans fused)
            int bb = row / S_;
            int sloc = row - bb * S_;
            int hh = colL >> 6, dd = colL & 63;
            int k = sloc & 63;
            int pos = ((k >> 2) & 3) * 16 + (k >> 4) * 4 + (k & 3);
            Vt[(((size_t)(bb * H_ + hh)) * HD_ + dd) * SPAD + (sloc >> 6) * 64 + pos] = f2bf(v);
          } else {
            outb[(size_t)row * D_ + colL] = f2bf(v);
          }
        }
      }
    }
  }
}

// ---- O GEMM, XCD-chunked, m97 structure (single 32KB buffer) ----
__global__ __launch_bounds__(256) void k_gemmo(const u16* __restrict__ A,
                                               const u16* __restrict__ Wt,
                                               const float* __restrict__ bias,
                                               float* __restrict__ outp) {
  int p = blockIdx.x;
  int gg = p & 7;
  int idx = p >> 3;
  int y = idx / 6;
  int x = gg * 6 + idx % 6;
  if (x >= 47) return;

  __shared__ u16 As[128 * 64];
  __shared__ u16 Bs[128 * 64];
  int tid = threadIdx.x;
  int lane = tid & 63;
  int wv = tid >> 6;
  int l16 = lane & 15, lg = lane >> 4;
  int wr = wv >> 1, wc = wv & 1;
  int m0 = x * 128, n0 = y * 128;

  int srow = tid >> 3;
  int csw = ((tid & 7) ^ (srow & 7)) * 8;
  const u16* asrc = A + csw;
  const u16* bsrc = Wt + csw;
  int dbase = wv * 8 * 64;

  f32x4 acc[4][4] = {};

#define STAGEG(tt) do {                                                  \
    int kk0 = (tt) * 64;                                                 \
    _Pragma("unroll")                                                    \
    for (int c = 0; c < 4; c++) {                                        \
      int row = srow + c * 32;                                           \
      int ar = m0 + row; if (ar > M_ - 1) ar = M_ - 1;                   \
      gl_lds16(asrc + (size_t)ar * D_ + kk0, &As[0] + dbase + c * 2048); \
      gl_lds16(bsrc + (size_t)(n0 + row) * D_ + kk0,                     \
               &Bs[0] + dbase + c * 2048);                               \
    }                                                                    \
  } while (0)

  for (int t = 0; t < 20; t++) {
    STAGEG(t);
    __syncthreads();
    #pragma unroll
    for (int kk = 0; kk < 2; kk++) {
      int pcol = ((kk * 4 + lg) ^ (l16 & 7)) * 8;
      bf16x8 af[4], bf[4];
      #pragma unroll
      for (int m = 0; m < 4; m++)
        af[m] = *(const bf16x8*)&As[(wr * 64 + m * 16 + l16) * 64 + pcol];
      #pragma unroll
      for (int n = 0; n < 4; n++)
        bf[n] = *(const bf16x8*)&Bs[(wc * 64 + n * 16 + l16) * 64 + pcol];
      __builtin_amdgcn_s_setprio(1);
      #pragma unroll
      for (int m = 0; m < 4; m++)
        #pragma unroll
        for (int n = 0; n < 4; n++)
          acc[m][n] = MFMA(af[m], bf[n], acc[m][n], 0, 0, 0);
      __builtin_amdgcn_s_setprio(0);
    }
    __syncthreads();
  }
#undef STAGEG

  #pragma unroll
  for (int m = 0; m < 4; m++) {
    int row0 = m0 + wr * 64 + m * 16 + lg * 4;
    #pragma unroll
    for (int n = 0; n < 4; n++) {
      int col = n0 + wc * 64 + n * 16 + l16;
      float bv = bias[col];
      #pragma unroll
      for (int j = 0; j < 4; j++) {
        int row = row0 + j;
        if (row < M_) outp[(size_t)row * D_ + col] = acc[m][n][j] + bv;
      }
    }
  }
}

// ---- Flash attention: 4 waves x TWO q-groups, KVB=64, dbuf K/V.
// Mask register-free fast path; l-partials reduced in epilogue. ----
__global__ __launch_bounds__(256) void k_attn(const u16* __restrict__ Qb,
                                              const u16* __restrict__ Kb,
                                              const u16* __restrict__ Vt,
                                              const float* __restrict__ mask,
                                              const int* __restrict__ mflag,
                                              u16* __restrict__ Ctx) {
  __shared__ u16 Kl[2][64 * 64];
  __shared__ u16 Vl[2][64 * 64];

  int p = blockIdx.x;
  int L = (p & 7) * 120 + (p >> 3);
  int h = L % 20;
  int g = L / 20;
  int b = g / 12;
  int xq = g % 12;
  int bh = b * H_ + h;
  int um = mflag[b];

  int tid = threadIdx.x;
  int lane = tid & 63, wv = tid >> 6;
  int l16 = lane & 15, lg = lane >> 4;
  int qw0 = xq * 128 + wv * 16;

  int qr0 = qw0 + l16;      if (qr0 > S_ - 1) qr0 = S_ - 1;
  int qr1 = qw0 + 64 + l16; if (qr1 > S_ - 1) qr1 = S_ - 1;
  const u16* qp0 = Qb + ((size_t)(b * S_ + qr0)) * D_ + h * HD_ + lg * 8;
  const u16* qp1 = Qb + ((size_t)(b * S_ + qr1)) * D_ + h * HD_ + lg * 8;
  bf16x8 aq00 = *(const bf16x8*)(qp0);
  bf16x8 aq01 = *(const bf16x8*)(qp0 + 32);
  bf16x8 aq10 = *(const bf16x8*)(qp1);
  bf16x8 aq11 = *(const bf16x8*)(qp1 + 32);
  const float* mrow0 = mask + (size_t)b * S_ * S_ + (size_t)qr0 * S_;
  const float* mrow1 = mask + (size_t)b * S_ * S_ + (size_t)qr1 * S_;

  int sr0 = wv * 16 + (lane >> 3);
  int csw = ((lane & 7) ^ (lane >> 3)) * 8;
  const u16* ksrc = Kb + (size_t)b * S_ * D_ + h * HD_ + csw;
  const u16* vsrc0 = Vt + ((size_t)bh * HD_ + sr0) * SPAD + csw;
  const u16* vsrc1 = vsrc0 + 8 * SPAD;

  float m0_ = BIGNEG, l0_ = 0.0f, m1_ = BIGNEG, l1_ = 0.0f;
  f32x4 acc0[4] = {}, acc1[4] = {};
  const f32x4 zf = {0, 0, 0, 0};

#define STAGE(k0s, bufb) do {                                          \
    int key0_ = (k0s) + sr0;     if (key0_ > S_ - 1) key0_ = S_ - 1;   \
    int key1_ = key0_ + 8;       if (key1_ > S_ - 1) key1_ = S_ - 1;   \
    u16* kd_ = &Kl[bufb][0] + wv * 1024;                               \
    u16* vd_ = &Vl[bufb][0] + wv * 1024;                               \
    gl_lds16(ksrc + (size_t)key0_ * D_, kd_);                          \
    gl_lds16(ksrc + (size_t)key1_ * D_, kd_ + 512);                    \
    gl_lds16(vsrc0 + (k0s), vd_);                                      \
    gl_lds16(vsrc1 + (k0s), vd_ + 512);                                \
  } while (0)

#define SMX(sv, mm, ll, accv) do {                                     \
    float t0 = fmaxf(fmaxf(sv[0][0], sv[0][1]), fmaxf(sv[0][2], sv[0][3])); \
    float t1 = fmaxf(fmaxf(sv[1][0], sv[1][1]), fmaxf(sv[1][2], sv[1][3])); \
    float t2 = fmaxf(fmaxf(sv[2][0], sv[2][1]), fmaxf(sv[2][2], sv[2][3])); \
    float t3 = fmaxf(fmaxf(sv[3][0], sv[3][1]), fmaxf(sv[3][2], sv[3][3])); \
    float rmax = fmaxf(fmaxf(t0, t1), fmaxf(t2, t3));                  \
    rmax = fmaxf(rmax, __shfl_xor(rmax, 16));                          \
    rmax = fmaxf(rmax, __shfl_xor(rmax, 32));                          \
    float mn = fmaxf(mm, rmax);                                        \
    if (!__all(mn - mm <= 8.0f)) {                                     \
      float c = __builtin_amdgcn_exp2f(mm - mn);                       \
      mm = mn; ll *= c;                                                \
      _Pragma("unroll")                                                \
      for (int j = 0; j < 4; j++) {                                    \
        float cj = __shfl(c, lg * 4 + j);                              \
        accv[0][j] *= cj; accv[1][j] *= cj;                            \
        accv[2][j] *= cj; accv[3][j] *= cj;                            \
      }                                                                \
    }                                                                  \
    _Pragma("unroll")                                                  \
    for (int sub = 0; sub < 4; sub++)                                  \
      _Pragma("unroll")                                                \
      for (int j = 0; j < 4; j++)                                      \
        sv[sub][j] = __builtin_amdgcn_exp2f(sv[sub][j] - mm);          \
    float a0 = (sv[0][0] + sv[0][1]) + (sv[0][2] + sv[0][3]);          \
    float a1 = (sv[1][0] + sv[1][1]) + (sv[1][2] + sv[1][3]);          \
    float a2 = (sv[2][0] + sv[2][1]) + (sv[2][2] + sv[2][3]);          \
    float a3 = (sv[3][0] + sv[3][1]) + (sv[3][2] + sv[3][3]);          \
    ll += (a0 + a1) + (a2 + a3);                                       \
  } while (0)

#define COMPUTE(curb, k0_, LASTV) do {                                 \
    const u16* KlC = &Kl[curb][0];                                     \
    const u16* VlC = &Vl[curb][0];                                     \
    f32x4 s0[4], s1[4];                                                \
    __builtin_amdgcn_s_setprio(1);                                     \
    _Pragma("unroll")                                                  \
    for (int sub = 0; sub < 4; sub++) {                                \
      const u16* kb = KlC + (sub * 16 + l16) * 64;                     \
      bf16x8 kf0 = *(const bf16x8*)(kb + ((lg     ^ (l16 & 7)) * 8));  \
      bf16x8 kf1 = *(const bf16x8*)(kb + (((4+lg) ^ (l16 & 7)) * 8));  \
      s0[sub] = MFMA(kf0, aq00, zf, 0, 0, 0);                          \
      s0[sub] = MFMA(kf1, aq01, s0[sub], 0, 0, 0);                     \
      s1[sub] = MFMA(kf0, aq10, zf, 0, 0, 0);                          \
      s1[sub] = MFMA(kf1, aq11, s1[sub], 0, 0, 0);                     \
    }                                                                  \
    __builtin_amdgcn_s_setprio(0);                                     \
    if (um) {                                                          \
      _Pragma("unroll")                                                \
      for (int sub = 0; sub < 4; sub++) {                              \
        int mc = (k0_) + sub * 16 + lg * 4;                            \
        if (mc > S_ - 4) mc = S_ - 4;                                  \
        float4 mv0 = *(const float4*)(mrow0 + mc);                     \
        float4 mv1 = *(const float4*)(mrow1 + mc);                     \
        s0[sub][0] = fmaf(mv0.x, LOG2E, s0[sub][0]);                   \
        s0[sub][1] = fmaf(mv0.y, LOG2E, s0[sub][1]);                   \
        s0[sub][2] = fmaf(mv0.z, LOG2E, s0[sub][2]);                   \
        s0[sub][3] = fmaf(mv0.w, LOG2E, s0[sub][3]);                   \
        s1[sub][0] = fmaf(mv1.x, LOG2E, s1[sub][0]);                   \
        s1[sub][1] = fmaf(mv1.y, LOG2E, s1[sub][1]);                   \
        s1[sub][2] = fmaf(mv1.z, LOG2E, s1[sub][2]);                   \
        s1[sub][3] = fmaf(mv1.w, LOG2E, s1[sub][3]);                   \
      }                                                                \
    }                                                                  \
    if (LASTV) {                                                       \
      _Pragma("unroll")                                                \
      for (int sub = 0; sub < 4; sub++) {                              \
        int kb_ = (k0_) + sub * 16 + lg * 4;                           \
        _Pragma("unroll")                                              \
        for (int j = 0; j < 4; j++)                                    \
          if (kb_ + j >= S_) { s0[sub][j] = BIGNEG; s1[sub][j] = BIGNEG; } \
      }                                                                \
    }                                                                  \
    SMX(s0, m0_, l0_, acc0);                                           \
    union { u32x4v u; bf16x8 bf; } pA0, pA1;                           \
    pA0.u[0] = cvtpk(s0[0][0], s0[0][1]); pA0.u[1] = cvtpk(s0[0][2], s0[0][3]); \
    pA0.u[2] = cvtpk(s0[1][0], s0[1][1]); pA0.u[3] = cvtpk(s0[1][2], s0[1][3]); \
    pA1.u[0] = cvtpk(s0[2][0], s0[2][1]); pA1.u[1] = cvtpk(s0[2][2], s0[2][3]); \
    pA1.u[2] = cvtpk(s0[3][0], s0[3][1]); pA1.u[3] = cvtpk(s0[3][2], s0[3][3]); \
    SMX(s1, m1_, l1_, acc1);                                           \
    union { u32x4v u; bf16x8 bf; } pB0, pB1;                           \
    pB0.u[0] = cvtpk(s1[0][0], s1[0][1]); pB0.u[1] = cvtpk(s1[0][2], s1[0][3]); \
    pB0.u[2] = cvtpk(s1[1][0], s1[1][1]); pB0.u[3] = cvtpk(s1[1][2], s1[1][3]); \
    pB1.u[0] = cvtpk(s1[2][0], s1[2][1]); pB1.u[1] = cvtpk(s1[2][2], s1[2][3]); \
    pB1.u[2] = cvtpk(s1[3][0], s1[3][1]); pB1.u[3] = cvtpk(s1[3][2], s1[3][3]); \
    __builtin_amdgcn_s_setprio(1);                                     \
    _Pragma("unroll")                                                  \
    for (int n = 0; n < 4; n++) {                                      \
      const u16* vb = VlC + (n * 16 + l16) * 64;                       \
      bf16x8 bv0 = *(const bf16x8*)(vb + (((lg*2  ) ^ (l16 & 7)) * 8));\
      bf16x8 bv1 = *(const bf16x8*)(vb + (((lg*2+1) ^ (l16 & 7)) * 8));\
      acc0[n] = MFMA(pA0.bf, bv0, acc0[n], 0, 0, 0);                   \
      acc0[n] = MFMA(pA1.bf, bv1, acc0[n], 0, 0, 0);                   \
      acc1[n] = MFMA(pB0.bf, bv0, acc1[n], 0, 0, 0);                   \
      acc1[n] = MFMA(pB1.bf, bv1, acc1[n], 0, 0, 0);                   \
    }                                                                  \
    __builtin_amdgcn_s_setprio(0);                                     \
  } while (0)

  STAGE(0, 0);

  for (int t = 0; t < NTA - 1; t++) {
    int k0 = t * KVB;
    __builtin_amdgcn_s_barrier();
    asm volatile("" ::: "memory");
    STAGE(k0 + KVB, (t + 1) & 1);
    asm volatile("s_waitcnt vmcnt(4)" ::: "memory");
    __builtin_amdgcn_s_barrier();
    asm volatile("" ::: "memory");
    COMPUTE(t & 1, k0, false);
  }
  {
    const int k0 = (NTA - 1) * KVB;   // 1472, tail = 28 keys
    __builtin_amdgcn_s_barrier();
    asm volatile("s_waitcnt vmcnt(0)" ::: "memory");
    __builtin_amdgcn_s_barrier();
    asm volatile("" ::: "memory");
    COMPUTE((NTA - 1) & 1, k0, true);
  }

  // epilogue: reduce the per-lane partial l across the 4 lane-groups
  l0_ += __shfl_xor(l0_, 16);
  l0_ += __shfl_xor(l0_, 32);
  l1_ += __shfl_xor(l1_, 16);
  l1_ += __shfl_xor(l1_, 32);
  float inv0 = 1.0f / l0_;
  float inv1 = 1.0f / l1_;
  #pragma unroll
  for (int j = 0; j < 4; j++) {
    float ivj0 = __shfl(inv0, lg * 4 + j);
    float ivj1 = __shfl(inv1, lg * 4 + j);
    int row0 = qw0 + lg * 4 + j;
    int row1 = row0 + 64;
    if (row0 < S_) {
      #pragma unroll
      for (int n = 0; n < 4; n++)
        Ctx[((size_t)(b * S_ + row0)) * D_ + h * HD_ + n * 16 + l16] = f2bf(acc0[n][j] * ivj0);
    }
    if (row1 < S_) {
      #pragma unroll
      for (int n = 0; n < 4; n++)
        Ctx[((size_t)(b * S_ + row1)) * D_ + h * HD_ + n * 16 + l16] = f2bf(acc1[n][j] * ivj1);
    }
  }
#undef STAGE
#undef SMX
#undef COMPUTE
}

extern "C" void kernel_launch(void* const* d_in, const int* in_sizes, int n_in,
                              void* d_out, int out_size, void* d_ws, size_t ws_size,
                              hipStream_t stream) {
  const float* hs   = (const float*)d_in[0];
  const float* mask = (const float*)d_in[1];
  const float* q_w  = (const float*)d_in[2];
  const float* q_b  = (const float*)d_in[3];
  const float* k_w  = (const float*)d_in[4];
  const float* v_w  = (const float*)d_in[5];
  const float* v_b  = (const float*)d_in[6];
  const float* o_w  = (const float*)d_in[7];
  const float* o_b  = (const float*)d_in[8];
  float* out = (float*)d_out;

  char* w = (char*)d_ws;
  const size_t XD = (size_t)M_ * D_;
  const size_t WD = (size_t)D_ * D_;
  u16* Xb  = (u16*)(w);                 w += XD * 2;
  u16* Wtq = (u16*)(w);                 w += WD * 2;   // q,k,v,o contiguous
  u16* Wtk = (u16*)(w);                 w += WD * 2;
  u16* Wtv = (u16*)(w);                 w += WD * 2;
  u16* Wto = (u16*)(w);                 w += WD * 2;
  u16* Qb  = (u16*)(w);                 w += XD * 2;   // q,k,(v unused third) contiguous
  u16* Kb  = (u16*)(w);                 w += XD * 2;
  u16* Vb  = (u16*)(w);                 w += XD * 2;   // unused (V goes straight to Vt)
  u16* Vt  = (u16*)(w);                 w += (size_t)B_ * H_ * HD_ * SPAD * 2;
  int* mflag = (int*)(w);               w += 4 * sizeof(int);
  u16* Ctx = Xb;   // alias: Xb dead after QKV projection
  (void)Wtk; (void)Wtv; (void)Vb;

  hipMemsetAsync(mflag, 0, 4 * sizeof(int), stream);
  k_conv<<<dim3(3750 + 1024), dim3(256), 0, stream>>>(hs, Xb, mask, mflag);
  k_trans4<<<dim3(40, 40, 4), dim3(256), 0, stream>>>(q_w, k_w, v_w, o_w, Wtq);

  k_gemmqkv<<<dim3(1440), dim3(256), 0, stream>>>(Xb, Wtq, q_b, v_b, Qb, Vt);

  k_attn<<<dim3(960), dim3(256), 0, stream>>>(Qb, Kb, Vt, mask, mflag, Ctx);

  k_gemmo<<<dim3(480), dim3(256), 0, stream>>>(Ctx, Wto, o_b, out);
}

// Round 25
// 224.037 us; speedup vs baseline: 1.0436x; 1.0436x over previous
//
#include <hip/hip_runtime.h>
#include <hip/hip_bf16.h>
#include <cstddef>

#define B_   4
#define S_   1500
#define D_   1280
#define H_   20
#define HD_  64
#define M_   (B_*S_)
#define SPAD 1536
#define BIGNEG (-1e30f)
#define LOG2E 1.44269504088896340736f
#define KVB  64
#define NTA  24   // ceil(1500/64)

typedef short bf16x8 __attribute__((ext_vector_type(8)));
typedef float f32x4 __attribute__((ext_vector_type(4)));
typedef unsigned short u16;
typedef u16 u16x8 __attribute__((ext_vector_type(8)));
typedef unsigned int u32x4v __attribute__((ext_vector_type(4)));

#define MFMA __builtin_amdgcn_mfma_f32_16x16x32_bf16

__device__ __forceinline__ u16 f2bf(float f) {
  union { float f; unsigned u; } x; x.f = f;
  unsigned r = (x.u + 0x7fffu + ((x.u >> 16) & 1u)) >> 16;
  return (u16)r;
}

__device__ __forceinline__ unsigned cvtpk(float a, float b) {
  unsigned r;
  asm volatile("v_cvt_pk_bf16_f32 %0, %1, %2" : "=v"(r) : "v"(a), "v"(b));
  return r;
}

__device__ __forceinline__ void gl_lds16(const u16* g, u16* l) {
  typedef __attribute__((address_space(1))) const unsigned GU;
  typedef __attribute__((address_space(3))) unsigned LU;
  __builtin_amdgcn_global_load_lds((GU*)g, (LU*)l, 16, 0, 0);
}

// ---- fused: fp32->bf16 convert (blocks 0..3749) + mask zero-scan (rest) ----
__global__ __launch_bounds__(256) void k_conv(const float* __restrict__ X, u16* __restrict__ Y,
                                              const float* __restrict__ msk, int* __restrict__ flag) {
  if (blockIdx.x < 3750) {
    size_t i = (size_t)blockIdx.x * 256 + threadIdx.x;
    const float4* p = (const float4*)(X + i * 8);
    float4 a = p[0], b = p[1];
    u16x8 v;
    v[0]=f2bf(a.x); v[1]=f2bf(a.y); v[2]=f2bf(a.z); v[3]=f2bf(a.w);
    v[4]=f2bf(b.x); v[5]=f2bf(b.y); v[6]=f2bf(b.z); v[7]=f2bf(b.w);
    *(u16x8*)(Y + i * 8) = v;
  } else {
    const size_t tot = (size_t)B_ * S_ * S_;
    size_t i = ((size_t)(blockIdx.x - 3750) * 256 + threadIdx.x) * 4;
    size_t stride = (size_t)1024 * 256 * 4;
    for (; i < tot; i += stride) {
      float4 v = *(const float4*)(msk + i);
      if (v.x != 0.f || v.y != 0.f || v.z != 0.f || v.w != 0.f) {
        int b = (int)(i / ((size_t)S_ * S_));
        atomicOr(&flag[b], 1);
      }
    }
  }
}

// ---- 4 weights W[k][n] fp32 -> Wt[n][k] bf16 transpose, z-selected ----
__global__ __launch_bounds__(256) void k_trans4(const float* __restrict__ qw,
                                                const float* __restrict__ kw,
                                                const float* __restrict__ vw,
                                                const float* __restrict__ ow,
                                                u16* __restrict__ Wt) {
  const float* W = (blockIdx.z == 0) ? qw : (blockIdx.z == 1) ? kw
                   : (blockIdx.z == 2) ? vw : ow;
  u16* dst = Wt + (size_t)blockIdx.z * D_ * D_;
  __shared__ float t[32][33];
  int n0 = blockIdx.x * 32, k0 = blockIdx.y * 32;
  int tx = threadIdx.x & 31, ty = threadIdx.x >> 5;
  #pragma unroll
  for (int i = ty; i < 32; i += 8) t[i][tx] = W[(size_t)(k0 + i) * D_ + n0 + tx];
  __syncthreads();
  #pragma unroll
  for (int i = ty; i < 32; i += 8) dst[(size_t)(n0 + i) * D_ + k0 + tx] = f2bf(t[tx][i]);
}

// ---- Vb[M][D] bf16 -> Vt[bh][d][SPAD] bf16, 64-key blocks in PV slot order ----
__global__ __launch_bounds__(256) void k_vtrans(const u16* __restrict__ Vb, u16* __restrict__ Vt) {
  __shared__ u16 t[128][72];
  int bh = blockIdx.x, b = bh / H_, h = bh % H_;
  int s0 = blockIdx.y * 128;
  int tid = threadIdx.x;
  #pragma unroll
  for (int r = 0; r < 4; r++) {
    int sl = r * 32 + (tid >> 3);
    int s = s0 + sl; if (s > S_ - 1) s = S_ - 1;
    bf16x8 v = *(const bf16x8*)(Vb + ((size_t)(b * S_ + s)) * D_ + h * HD_ + (tid & 7) * 8);
    *(bf16x8*)&t[sl][(tid & 7) * 8] = v;
  }
  __syncthreads();
  #pragma unroll
  for (int r = 0; r < 4; r++) {
    int d = r * 16 + (tid >> 4);
    int ss = (tid & 15) * 8;
    u16x8 o;
    #pragma unroll
    for (int q = 0; q < 8; q++) {
      int sl = ss + q;
      int kk = ((sl >> 4) & 3) * 4 + (sl & 3) + ((sl >> 2) & 3) * 16 + (sl & 64);
      o[q] = t[kk][d];
    }
    *(u16x8*)(Vt + ((size_t)bh * HD_ + d) * SPAD + s0 + ss) = o;
  }
}

// ---- Fused QKV GEMM, XCD-chunked, m97 structure: BK=64, SINGLE 32KB buffer ----
__global__ __launch_bounds__(256) void k_gemmqkv(const u16* __restrict__ A,
                                                 const u16* __restrict__ Wt,
                                                 const float* __restrict__ q_b,
                                                 const float* __restrict__ v_b,
                                                 u16* __restrict__ Qb) {
  int p = blockIdx.x;
  int gg = p & 7;
  int idx = p >> 3;
  int y = idx / 6;
  int x = gg * 6 + idx % 6;
  if (x >= 47) return;

  __shared__ u16 As[128 * 64];
  __shared__ u16 Bs[128 * 64];
  int tid = threadIdx.x;
  int lane = tid & 63;
  int wv = tid >> 6;
  int l16 = lane & 15, lg = lane >> 4;
  int wr = wv >> 1, wc = wv & 1;
  int m0 = x * 128;
  int n0g = y * 128;
  int sel = y / 10;
  int nloc = n0g - sel * 1280;

  int srow = tid >> 3;
  int csw = ((tid & 7) ^ (srow & 7)) * 8;
  const u16* asrc = A + csw;
  const u16* bsrc = Wt + csw;
  int dbase = wv * 8 * 64;

  f32x4 acc[4][4] = {};

#define STAGEG(tt) do {                                                  \
    int kk0 = (tt) * 64;                                                 \
    _Pragma("unroll")                                                    \
    for (int c = 0; c < 4; c++) {                                        \
      int row = srow + c * 32;                                           \
      int ar = m0 + row; if (ar > M_ - 1) ar = M_ - 1;                   \
      gl_lds16(asrc + (size_t)ar * D_ + kk0, &As[0] + dbase + c * 2048); \
      gl_lds16(bsrc + (size_t)(n0g + row) * D_ + kk0,                    \
               &Bs[0] + dbase + c * 2048);                               \
    }                                                                    \
  } while (0)

  for (int t = 0; t < 20; t++) {
    STAGEG(t);
    __syncthreads();
    #pragma unroll
    for (int kk = 0; kk < 2; kk++) {
      int pcol = ((kk * 4 + lg) ^ (l16 & 7)) * 8;
      bf16x8 af[4], bf[4];
      #pragma unroll
      for (int m = 0; m < 4; m++)
        af[m] = *(const bf16x8*)&As[(wr * 64 + m * 16 + l16) * 64 + pcol];
      #pragma unroll
      for (int n = 0; n < 4; n++)
        bf[n] = *(const bf16x8*)&Bs[(wc * 64 + n * 16 + l16) * 64 + pcol];
      __builtin_amdgcn_s_setprio(1);
      #pragma unroll
      for (int m = 0; m < 4; m++)
        #pragma unroll
        for (int n = 0; n < 4; n++)
          acc[m][n] = MFMA(af[m], bf[n], acc[m][n], 0, 0, 0);
      __builtin_amdgcn_s_setprio(0);
    }
    __syncthreads();
  }
#undef STAGEG

  const float* bias = (sel == 0) ? q_b : v_b;
  float scl = (sel == 0) ? (0.125f * LOG2E) : 1.0f;
  u16* outb = Qb + (size_t)sel * ((size_t)M_ * D_);

  #pragma unroll
  for (int m = 0; m < 4; m++) {
    int row0 = m0 + wr * 64 + m * 16 + lg * 4;
    #pragma unroll
    for (int n = 0; n < 4; n++) {
      int colL = nloc + wc * 64 + n * 16 + l16;
      float bv = (sel == 1) ? 0.0f : bias[colL];
      #pragma unroll
      for (int j = 0; j < 4; j++) {
        int row = row0 + j;
        if (row < M_) {
          float v = (acc[m][n][j] + bv) * scl;
          outb[(size_t)row * D_ + colL] = f2bf(v);
        }
      }
    }
  }
}

// ---- O GEMM, XCD-chunked, m97 structure (single 32KB buffer) ----
__global__ __launch_bounds__(256) void k_gemmo(const u16* __restrict__ A,
                                               const u16* __restrict__ Wt,
                                               const float* __restrict__ bias,
                                               float* __restrict__ outp) {
  int p = blockIdx.x;
  int gg = p & 7;
  int idx = p >> 3;
  int y = idx / 6;
  int x = gg * 6 + idx % 6;
  if (x >= 47) return;

  __shared__ u16 As[128 * 64];
  __shared__ u16 Bs[128 * 64];
  int tid = threadIdx.x;
  int lane = tid & 63;
  int wv = tid >> 6;
  int l16 = lane & 15, lg = lane >> 4;
  int wr = wv >> 1, wc = wv & 1;
  int m0 = x * 128, n0 = y * 128;

  int srow = tid >> 3;
  int csw = ((tid & 7) ^ (srow & 7)) * 8;
  const u16* asrc = A + csw;
  const u16* bsrc = Wt + csw;
  int dbase = wv * 8 * 64;

  f32x4 acc[4][4] = {};

#define STAGEG(tt) do {                                                  \
    int kk0 = (tt) * 64;                                                 \
    _Pragma("unroll")                                                    \
    for (int c = 0; c < 4; c++) {                                        \
      int row = srow + c * 32;                                           \
      int ar = m0 + row; if (ar > M_ - 1) ar = M_ - 1;                   \
      gl_lds16(asrc + (size_t)ar * D_ + kk0, &As[0] + dbase + c * 2048); \
      gl_lds16(bsrc + (size_t)(n0 + row) * D_ + kk0,                     \
               &Bs[0] + dbase + c * 2048);                               \
    }                                                                    \
  } while (0)

  for (int t = 0; t < 20; t++) {
    STAGEG(t);
    __syncthreads();
    #pragma unroll
    for (int kk = 0; kk < 2; kk++) {
      int pcol = ((kk * 4 + lg) ^ (l16 & 7)) * 8;
      bf16x8 af[4], bf[4];
      #pragma unroll
      for (int m = 0; m < 4; m++)
        af[m] = *(const bf16x8*)&As[(wr * 64 + m * 16 + l16) * 64 + pcol];
      #pragma unroll
      for (int n = 0; n < 4; n++)
        bf[n] = *(const bf16x8*)&Bs[(wc * 64 + n * 16 + l16) * 64 + pcol];
      __builtin_amdgcn_s_setprio(1);
      #pragma unroll
      for (int m = 0; m < 4; m++)
        #pragma unroll
        for (int n = 0; n < 4; n++)
          acc[m][n] = MFMA(af[m], bf[n], acc[m][n], 0, 0, 0);
      __builtin_amdgcn_s_setprio(0);
    }
    __syncthreads();
  }
#undef STAGEG

  #pragma unroll
  for (int m = 0; m < 4; m++) {
    int row0 = m0 + wr * 64 + m * 16 + lg * 4;
    #pragma unroll
    for (int n = 0; n < 4; n++) {
      int col = n0 + wc * 64 + n * 16 + l16;
      float bv = bias[col];
      #pragma unroll
      for (int j = 0; j < 4; j++) {
        int row = row0 + j;
        if (row < M_) outp[(size_t)row * D_ + col] = acc[m][n][j] + bv;
      }
    }
  }
}

// ---- Flash attention: 4 waves x TWO q-groups, KVB=64, dbuf K/V.
// Mask register-free fast path; l-partials reduced in epilogue. ----
__global__ __launch_bounds__(256) void k_attn(const u16* __restrict__ Qb,
                                              const u16* __restrict__ Kb,
                                              const u16* __restrict__ Vt,
                                              const float* __restrict__ mask,
                                              const int* __restrict__ mflag,
                                              u16* __restrict__ Ctx) {
  __shared__ u16 Kl[2][64 * 64];
  __shared__ u16 Vl[2][64 * 64];

  int p = blockIdx.x;
  int L = (p & 7) * 120 + (p >> 3);
  int h = L % 20;
  int g = L / 20;
  int b = g / 12;
  int xq = g % 12;
  int bh = b * H_ + h;
  int um = mflag[b];

  int tid = threadIdx.x;
  int lane = tid & 63, wv = tid >> 6;
  int l16 = lane & 15, lg = lane >> 4;
  int qw0 = xq * 128 + wv * 16;

  int qr0 = qw0 + l16;      if (qr0 > S_ - 1) qr0 = S_ - 1;
  int qr1 = qw0 + 64 + l16; if (qr1 > S_ - 1) qr1 = S_ - 1;
  const u16* qp0 = Qb + ((size_t)(b * S_ + qr0)) * D_ + h * HD_ + lg * 8;
  const u16* qp1 = Qb + ((size_t)(b * S_ + qr1)) * D_ + h * HD_ + lg * 8;
  bf16x8 aq00 = *(const bf16x8*)(qp0);
  bf16x8 aq01 = *(const bf16x8*)(qp0 + 32);
  bf16x8 aq10 = *(const bf16x8*)(qp1);
  bf16x8 aq11 = *(const bf16x8*)(qp1 + 32);
  const float* mrow0 = mask + (size_t)b * S_ * S_ + (size_t)qr0 * S_;
  const float* mrow1 = mask + (size_t)b * S_ * S_ + (size_t)qr1 * S_;

  int sr0 = wv * 16 + (lane >> 3);
  int csw = ((lane & 7) ^ (lane >> 3)) * 8;
  const u16* ksrc = Kb + (size_t)b * S_ * D_ + h * HD_ + csw;
  const u16* vsrc0 = Vt + ((size_t)bh * HD_ + sr0) * SPAD + csw;
  const u16* vsrc1 = vsrc0 + 8 * SPAD;

  float m0_ = BIGNEG, l0_ = 0.0f, m1_ = BIGNEG, l1_ = 0.0f;
  f32x4 acc0[4] = {}, acc1[4] = {};
  const f32x4 zf = {0, 0, 0, 0};

#define STAGE(k0s, bufb) do {                                          \
    int key0_ = (k0s) + sr0;     if (key0_ > S_ - 1) key0_ = S_ - 1;   \
    int key1_ = key0_ + 8;       if (key1_ > S_ - 1) key1_ = S_ - 1;   \
    u16* kd_ = &Kl[bufb][0] + wv * 1024;                               \
    u16* vd_ = &Vl[bufb][0] + wv * 1024;                               \
    gl_lds16(ksrc + (size_t)key0_ * D_, kd_);                          \
    gl_lds16(ksrc + (size_t)key1_ * D_, kd_ + 512);                    \
    gl_lds16(vsrc0 + (k0s), vd_);                                      \
    gl_lds16(vsrc1 + (k0s), vd_ + 512);                                \
  } while (0)

#define SMX(sv, mm, ll, accv) do {                                     \
    float t0 = fmaxf(fmaxf(sv[0][0], sv[0][1]), fmaxf(sv[0][2], sv[0][3])); \
    float t1 = fmaxf(fmaxf(sv[1][0], sv[1][1]), fmaxf(sv[1][2], sv[1][3])); \
    float t2 = fmaxf(fmaxf(sv[2][0], sv[2][1]), fmaxf(sv[2][2], sv[2][3])); \
    float t3 = fmaxf(fmaxf(sv[3][0], sv[3][1]), fmaxf(sv[3][2], sv[3][3])); \
    float rmax = fmaxf(fmaxf(t0, t1), fmaxf(t2, t3));                  \
    rmax = fmaxf(rmax, __shfl_xor(rmax, 16));                          \
    rmax = fmaxf(rmax, __shfl_xor(rmax, 32));                          \
    float mn = fmaxf(mm, rmax);                                        \
    if (!__all(mn - mm <= 8.0f)) {                                     \
      float c = __builtin_amdgcn_exp2f(mm - mn);                       \
      mm = mn; ll *= c;                                                \
      _Pragma("unroll")                                                \
      for (int j = 0; j < 4; j++) {                                    \
        float cj = __shfl(c, lg * 4 + j);                              \
        accv[0][j] *= cj; accv[1][j] *= cj;                            \
        accv[2][j] *= cj; accv[3][j] *= cj;                            \
      }                                                                \
    }                                                                  \
    _Pragma("unroll")                                                  \
    for (int sub = 0; sub < 4; sub++)                                  \
      _Pragma("unroll")                                                \
      for (int j = 0; j < 4; j++)                                      \
        sv[sub][j] = __builtin_amdgcn_exp2f(sv[sub][j] - mm);          \
    float a0 = (sv[0][0] + sv[0][1]) + (sv[0][2] + sv[0][3]);          \
    float a1 = (sv[1][0] + sv[1][1]) + (sv[1][2] + sv[1][3]);          \
    float a2 = (sv[2][0] + sv[2][1]) + (sv[2][2] + sv[2][3]);          \
    float a3 = (sv[3][0] + sv[3][1]) + (sv[3][2] + sv[3][3]);          \
    ll += (a0 + a1) + (a2 + a3);                                       \
  } while (0)

#define COMPUTE(curb, k0_, LASTV) do {                                 \
    const u16* KlC = &Kl[curb][0];                                     \
    const u16* VlC = &Vl[curb][0];                                     \
    f32x4 s0[4], s1[4];                                                \
    __builtin_amdgcn_s_setprio(1);                                     \
    _Pragma("unroll")                                                  \
    for (int sub = 0; sub < 4; sub++) {                                \
      const u16* kb = KlC + (sub * 16 + l16) * 64;                     \
      bf16x8 kf0 = *(const bf16x8*)(kb + ((lg     ^ (l16 & 7)) * 8));  \
      bf16x8 kf1 = *(const bf16x8*)(kb + (((4+lg) ^ (l16 & 7)) * 8));  \
      s0[sub] = MFMA(kf0, aq00, zf, 0, 0, 0);                          \
      s0[sub] = MFMA(kf1, aq01, s0[sub], 0, 0, 0);                     \
      s1[sub] = MFMA(kf0, aq10, zf, 0, 0, 0);                          \
      s1[sub] = MFMA(kf1, aq11, s1[sub], 0, 0, 0);                     \
    }                                                                  \
    __builtin_amdgcn_s_setprio(0);                                     \
    if (um) {                                                          \
      _Pragma("unroll")                                                \
      for (int sub = 0; sub < 4; sub++) {                              \
        int mc = (k0_) + sub * 16 + lg * 4;                            \
        if (mc > S_ - 4) mc = S_ - 4;                                  \
        float4 mv0 = *(const float4*)(mrow0 + mc);                     \
        float4 mv1 = *(const float4*)(mrow1 + mc);                     \
        s0[sub][0] = fmaf(mv0.x, LOG2E, s0[sub][0]);                   \
        s0[sub][1] = fmaf(mv0.y, LOG2E, s0[sub][1]);                   \
        s0[sub][2] = fmaf(mv0.z, LOG2E, s0[sub][2]);                   \
        s0[sub][3] = fmaf(mv0.w, LOG2E, s0[sub][3]);                   \
        s1[sub][0] = fmaf(mv1.x, LOG2E, s1[sub][0]);                   \
        s1[sub][1] = fmaf(mv1.y, LOG2E, s1[sub][1]);                   \
        s1[sub][2] = fmaf(mv1.z, LOG2E, s1[sub][2]);                   \
        s1[sub][3] = fmaf(mv1.w, LOG2E, s1[sub][3]);                   \
      }                                                                \
    }                                                                  \
    if (LASTV) {                                                       \
      _Pragma("unroll")                                                \
      for (int sub = 0; sub < 4; sub++) {                              \
        int kb_ = (k0_) + sub * 16 + lg * 4;                           \
        _Pragma("unroll")                                              \
        for (int j = 0; j < 4; j++)                                    \
          if (kb_ + j >= S_) { s0[sub][j] = BIGNEG; s1[sub][j] = BIGNEG; } \
      }                                                                \
    }                                                                  \
    SMX(s0, m0_, l0_, acc0);                                           \
    union { u32x4v u; bf16x8 bf; } pA0, pA1;                           \
    pA0.u[0] = cvtpk(s0[0][0], s0[0][1]); pA0.u[1] = cvtpk(s0[0][2], s0[0][3]); \
    pA0.u[2] = cvtpk(s0[1][0], s0[1][1]); pA0.u[3] = cvtpk(s0[1][2], s0[1][3]); \
    pA1.u[0] = cvtpk(s0[2][0], s0[2][1]); pA1.u[1] = cvtpk(s0[2][2], s0[2][3]); \
    pA1.u[2] = cvtpk(s0[3][0], s0[3][1]); pA1.u[3] = cvtpk(s0[3][2], s0[3][3]); \
    SMX(s1, m1_, l1_, acc1);                                           \
    union { u32x4v u; bf16x8 bf; } pB0, pB1;                           \
    pB0.u[0] = cvtpk(s1[0][0], s1[0][1]); pB0.u[1] = cvtpk(s1[0][2], s1[0][3]); \
    pB0.u[2] = cvtpk(s1[1][0], s1[1][1]); pB0.u[3] = cvtpk(s1[1][2], s1[1][3]); \
    pB1.u[0] = cvtpk(s1[2][0], s1[2][1]); pB1.u[1] = cvtpk(s1[2][2], s1[2][3]); \
    pB1.u[2] = cvtpk(s1[3][0], s1[3][1]); pB1.u[3] = cvtpk(s1[3][2], s1[3][3]); \
    __builtin_amdgcn_s_setprio(1);                                     \
    _Pragma("unroll")                                                  \
    for (int n = 0; n < 4; n++) {                                      \
      const u16* vb = VlC + (n * 16 + l16) * 64;                       \
      bf16x8 bv0 = *(const bf16x8*)(vb + (((lg*2  ) ^ (l16 & 7)) * 8));\
      bf16x8 bv1 = *(const bf16x8*)(vb + (((lg*2+1) ^ (l16 & 7)) * 8));\
      acc0[n] = MFMA(pA0.bf, bv0, acc0[n], 0, 0, 0);                   \
      acc0[n] = MFMA(pA1.bf, bv1, acc0[n], 0, 0, 0);                   \
      acc1[n] = MFMA(pB0.bf, bv0, acc1[n], 0, 0, 0);                   \
      acc1[n] = MFMA(pB1.bf, bv1, acc1[n], 0, 0, 0);                   \
    }                                                                  \
    __builtin_amdgcn_s_setprio(0);                                     \
  } while (0)

  STAGE(0, 0);

  for (int t = 0; t < NTA - 1; t++) {
    int k0 = t * KVB;
    __builtin_amdgcn_s_barrier();
    asm volatile("" ::: "memory");
    STAGE(k0 + KVB, (t + 1) & 1);
    asm volatile("s_waitcnt vmcnt(4)" ::: "memory");
    __builtin_amdgcn_s_barrier();
    asm volatile("" ::: "memory");
    COMPUTE(t & 1, k0, false);
  }
  {
    const int k0 = (NTA - 1) * KVB;   // 1472, tail = 28 keys
    __builtin_amdgcn_s_barrier();
    asm volatile("s_waitcnt vmcnt(0)" ::: "memory");
    __builtin_amdgcn_s_barrier();
    asm volatile("" ::: "memory");
    COMPUTE((NTA - 1) & 1, k0, true);
  }

  // epilogue: reduce the per-lane partial l across the 4 lane-groups
  l0_ += __shfl_xor(l0_, 16);
  l0_ += __shfl_xor(l0_, 32);
  l1_ += __shfl_xor(l1_, 16);
  l1_ += __shfl_xor(l1_, 32);
  float inv0 = 1.0f / l0_;
  float inv1 = 1.0f / l1_;
  #pragma unroll
  for (int j = 0; j < 4; j++) {
    float ivj0 = __shfl(inv0, lg * 4 + j);
    float ivj1 = __shfl(inv1, lg * 4 + j);
    int row0 = qw0 + lg * 4 + j;
    int row1 = row0 + 64;
    if (row0 < S_) {
      #pragma unroll
      for (int n = 0; n < 4; n++)
        Ctx[((size_t)(b * S_ + row0)) * D_ + h * HD_ + n * 16 + l16] = f2bf(acc0[n][j] * ivj0);
    }
    if (row1 < S_) {
      #pragma unroll
      for (int n = 0; n < 4; n++)
        Ctx[((size_t)(b * S_ + row1)) * D_ + h * HD_ + n * 16 + l16] = f2bf(acc1[n][j] * ivj1);
    }
  }
#undef STAGE
#undef SMX
#undef COMPUTE
}

extern "C" void kernel_launch(void* const* d_in, const int* in_sizes, int n_in,
                              void* d_out, int out_size, void* d_ws, size_t ws_size,
                              hipStream_t stream) {
  const float* hs   = (const float*)d_in[0];
  const float* mask = (const float*)d_in[1];
  const float* q_w  = (const float*)d_in[2];
  const float* q_b  = (const float*)d_in[3];
  const float* k_w  = (const float*)d_in[4];
  const float* v_w  = (const float*)d_in[5];
  const float* v_b  = (const float*)d_in[6];
  const float* o_w  = (const float*)d_in[7];
  const float* o_b  = (const float*)d_in[8];
  float* out = (float*)d_out;

  char* w = (char*)d_ws;
  const size_t XD = (size_t)M_ * D_;
  const size_t WD = (size_t)D_ * D_;
  u16* Xb  = (u16*)(w);                 w += XD * 2;
  u16* Wtq = (u16*)(w);                 w += WD * 2;   // q,k,v,o contiguous
  u16* Wtk = (u16*)(w);                 w += WD * 2;
  u16* Wtv = (u16*)(w);                 w += WD * 2;
  u16* Wto = (u16*)(w);                 w += WD * 2;
  u16* Qb  = (u16*)(w);                 w += XD * 2;   // q,k,v outputs contiguous
  u16* Kb  = (u16*)(w);                 w += XD * 2;
  u16* Vb  = (u16*)(w);                 w += XD * 2;
  u16* Vt  = (u16*)(w);                 w += (size_t)B_ * H_ * HD_ * SPAD * 2;
  int* mflag = (int*)(w);               w += 4 * sizeof(int);
  u16* Ctx = Xb;   // alias: Xb dead after QKV projection
  (void)Wtk; (void)Wtv;

  hipMemsetAsync(mflag, 0, 4 * sizeof(int), stream);
  k_conv<<<dim3(3750 + 1024), dim3(256), 0, stream>>>(hs, Xb, mask, mflag);
  k_trans4<<<dim3(40, 40, 4), dim3(256), 0, stream>>>(q_w, k_w, v_w, o_w, Wtq);

  k_gemmqkv<<<dim3(1440), dim3(256), 0, stream>>>(Xb, Wtq, q_b, v_b, Qb);
  k_vtrans<<<dim3(80, 12), dim3(256), 0, stream>>>(Vb, Vt);

  k_attn<<<dim3(960), dim3(256), 0, stream>>>(Qb, Kb, Vt, mask, mflag, Ctx);

  k_gemmo<<<dim3(480), dim3(256), 0, stream>>>(Ctx, Wto, o_b, out);
}